// Round 1
// baseline (362.299 us; speedup 1.0000x reference)
//
#include <hip/hip_runtime.h>
#include <hip/hip_bf16.h>
#include <hip/hip_fp16.h>

// ---------- types ----------
typedef __attribute__((ext_vector_type(8))) short    bf16x8;  // 8 bf16 (4 VGPRs) MFMA A/B frag
typedef __attribute__((ext_vector_type(4))) float    f32x4;   // MFMA C/D frag
typedef __attribute__((ext_vector_type(4))) _Float16 f16x4;   // 16x16x16 f16 frag

typedef const void __attribute__((address_space(1))) gvoid_t;
typedef void __attribute__((address_space(3)))       lvoid_t;

static __device__ __forceinline__ void gload_lds16(const void* g, void* l) {
    // HW semantics: LDS dest = wave-uniform base + lane*16B; global src is per-lane.
    __builtin_amdgcn_global_load_lds((gvoid_t*)g, (lvoid_t*)l, 16, 0, 0);
}

static __device__ __forceinline__ short bfbits(float f) {
    union { __hip_bfloat16 h; short s; } u;
    u.h = __float2bfloat16(f);
    return u.s;
}

// ---------- f32 -> bf16 convert (vectorized, 8 elems/thread) ----------
__global__ __launch_bounds__(256) void cvt_bf16_kernel(const float* __restrict__ src,
                                                       __hip_bfloat16* __restrict__ dst, int n8) {
    int t = blockIdx.x * 256 + threadIdx.x;
    if (t >= n8) return;
    float4 a = ((const float4*)src)[2 * t];
    float4 b = ((const float4*)src)[2 * t + 1];
    bf16x8 o;
    o[0] = bfbits(a.x); o[1] = bfbits(a.y); o[2] = bfbits(a.z); o[3] = bfbits(a.w);
    o[4] = bfbits(b.x); o[5] = bfbits(b.y); o[6] = bfbits(b.z); o[7] = bfbits(b.w);
    ((bf16x8*)dst)[t] = o;
}

// ---------- f32 [K][N] -> bf16 [Npad][K] transpose-convert (zero pad n>=N) ----------
__global__ __launch_bounds__(256) void transpose_cvt(const float* __restrict__ src,
                                                     __hip_bfloat16* __restrict__ dst,
                                                     int K, int N, int Npad) {
    __shared__ __hip_bfloat16 tile[64][72];
    const int kb = blockIdx.x * 64;
    const int nb = blockIdx.y * 64;
    const int c  = threadIdx.x & 63;
    const int r0 = threadIdx.x >> 6;
    if (nb < N) {
#pragma unroll
        for (int i = 0; i < 16; ++i) {
            int r = r0 + i * 4;  // k-local
            tile[r][c] = __float2bfloat16(src[(size_t)(kb + r) * N + nb + c]);
        }
        __syncthreads();
#pragma unroll
        for (int i = 0; i < 16; ++i) {
            int r = r0 + i * 4;  // n-local
            dst[(size_t)(nb + r) * K + kb + c] = tile[c][r];
        }
    } else {
        __hip_bfloat16 z = __float2bfloat16(0.0f);
#pragma unroll
        for (int i = 0; i < 16; ++i) {
            int r = r0 + i * 4;
            dst[(size_t)(nb + r) * K + kb + c] = z;
        }
    }
}

__global__ void pad_bias_kernel(const float* __restrict__ b, float* __restrict__ out, int n, int npad) {
    int t = blockIdx.x * blockDim.x + threadIdx.x;
    if (t < npad) out[t] = (t < n) ? b[t] : 0.0f;
}

// ---------- GEMM: C[M][N] = A[M][K](bf16) @ Bt[N][K]^T(bf16) + bias ----------
// m97 structure: 128x128 tile, BK=32, 4 waves each 64x64 (4x4 16x16 frags).
// OUTMODE: 0 = bf16, 1 = f32, 2 = f16
template <int OUTMODE>
__global__ __launch_bounds__(256) void gemm_bt(const __hip_bfloat16* __restrict__ A,
                                               const __hip_bfloat16* __restrict__ Bt,
                                               const float* __restrict__ bias,
                                               void* __restrict__ Cout,
                                               int M, int N, int K) {
    __shared__ __align__(16) __hip_bfloat16 sA[128 * 32];
    __shared__ __align__(16) __hip_bfloat16 sB[128 * 32];
    const int tid  = threadIdx.x;
    const int wid  = tid >> 6;
    const int lane = tid & 63;
    const int lr   = lane & 15;
    const int lg   = lane >> 4;
    const int mb   = blockIdx.y * 128;
    const int nb   = blockIdx.x * 128;
    const int wr   = (wid >> 1) * 64;
    const int wc   = (wid & 1) * 64;

    f32x4 acc[4][4] = {};

    for (int k0 = 0; k0 < K; k0 += 32) {
#pragma unroll
        for (int j = 0; j < 2; ++j) {
            int e   = wid * 1024 + j * 512 + lane * 8;  // element idx in 128x32 tile
            int row = e >> 5;
            int col = e & 31;
            gload_lds16(A + (size_t)(mb + row) * K + (k0 + col), &sA[wid * 1024 + j * 512]);
            gload_lds16(Bt + (size_t)(nb + row) * K + (k0 + col), &sB[wid * 1024 + j * 512]);
        }
        asm volatile("s_waitcnt vmcnt(0)" ::: "memory");
        __syncthreads();
        bf16x8 af[4], bfr[4];
#pragma unroll
        for (int m = 0; m < 4; ++m)
            af[m] = *(const bf16x8*)&sA[(wr + m * 16 + lr) * 32 + lg * 8];
#pragma unroll
        for (int n = 0; n < 4; ++n)
            bfr[n] = *(const bf16x8*)&sB[(wc + n * 16 + lr) * 32 + lg * 8];
#pragma unroll
        for (int m = 0; m < 4; ++m)
#pragma unroll
            for (int n = 0; n < 4; ++n)
                acc[m][n] = __builtin_amdgcn_mfma_f32_16x16x32_bf16(af[m], bfr[n], acc[m][n], 0, 0, 0);
        __syncthreads();
    }

#pragma unroll
    for (int n = 0; n < 4; ++n) {
        int col  = nb + wc + n * 16 + lr;
        float bv = bias ? bias[col] : 0.0f;
#pragma unroll
        for (int m = 0; m < 4; ++m) {
#pragma unroll
            for (int r = 0; r < 4; ++r) {
                int row    = mb + wr + m * 16 + lg * 4 + r;  // C row = (lane>>4)*4+reg (m89)
                float val  = acc[m][n][r] + bv;
                size_t idx = (size_t)row * N + col;
                if constexpr (OUTMODE == 1)      ((float*)Cout)[idx] = val;
                else if constexpr (OUTMODE == 2) ((_Float16*)Cout)[idx] = (_Float16)val;
                else                             ((__hip_bfloat16*)Cout)[idx] = __float2bfloat16(val);
            }
        }
    }
}

// ---------- RoPE (faithful quirk: cos_pos=sin(pe), sin_pos=cos(pe)), in-place ----------
__global__ __launch_bounds__(256) void rope_kernel(__hip_bfloat16* __restrict__ x,
                                                   int rows, int heads, int rowstride, int S) {
    int t = blockIdx.x * 256 + threadIdx.x;
    if (t >= rows * heads * 32) return;
    int i   = t & 31;
    int hh  = (t >> 5) % heads;
    int row = t / (heads * 32);
    int pos = row % S;
    // theta = 10000^(-2i/64) = exp(-i * (2/64)*ln(10000))
    float theta = __expf(-0.28782313662425572f * (float)i);
    float pe = (float)pos * theta;
    float sp, cp;
    sincosf(pe, &sp, &cp);
    size_t idx = (size_t)row * rowstride + hh * 64 + 2 * i;
    float x0 = __bfloat162float(x[idx]);
    float x1 = __bfloat162float(x[idx + 1]);
    // out[2i] = x0*sin - x1*cos ; out[2i+1] = x1*sin + x0*cos
    x[idx]     = __float2bfloat16(x0 * sp - x1 * cp);
    x[idx + 1] = __float2bfloat16(x1 * sp + x0 * cp);
}

// ---------- Flash attention ----------
// grid (S/128, H=16, B=2), 256 thr (4 waves), wave owns 32 q rows (2 groups of 16).
// Swapped QK^T: mfma(K, Q) -> C col=q (lane&15), row=key ((lane>>4)*4+reg).
// PV: mfma_f32_16x16x16f16(V^T, P^T): B-frag k-index (lane>>4)*4+j == C-row map, no transpose.
__global__ __launch_bounds__(256) void attn_kernel(const __hip_bfloat16* __restrict__ qtc,
                                                   const __hip_bfloat16* __restrict__ qr,
                                                   const __hip_bfloat16* __restrict__ ktc,
                                                   const __hip_bfloat16* __restrict__ kr,
                                                   const _Float16* __restrict__ vtc,
                                                   __hip_bfloat16* __restrict__ outp,
                                                   int S) {
    const int tid  = threadIdx.x;
    const int wid  = tid >> 6;
    const int lane = tid & 63;
    const int lr   = lane & 15;
    const int lg   = lane >> 4;
    const int h    = blockIdx.y;
    const int b    = blockIdx.z;
    const size_t base = (size_t)b * S;
    const int qb   = blockIdx.x * 128 + wid * 32;

    bf16x8 qf[2][4];
#pragma unroll
    for (int g = 0; g < 2; ++g) {
        size_t rowoff = (base + qb + g * 16 + lr) << 10;
        const __hip_bfloat16* pq  = qtc + rowoff + h * 64;
        const __hip_bfloat16* pqr = qr + rowoff + h * 64;
        qf[g][0] = *(const bf16x8*)(pq + lg * 8);
        qf[g][1] = *(const bf16x8*)(pq + 32 + lg * 8);
        qf[g][2] = *(const bf16x8*)(pqr + lg * 8);
        qf[g][3] = *(const bf16x8*)(pqr + 32 + lg * 8);
    }

    f32x4 oacc[2][4] = {};
    float mrun[2] = {-3.0e38f, -3.0e38f};
    float lrun[2] = {0.0f, 0.0f};

    for (int kt = 0; kt < S; kt += 16) {
        bf16x8 kf[4];
        {
            size_t rowoff = (base + kt + lr) << 10;
            const __hip_bfloat16* pk  = ktc + rowoff + h * 64;
            const __hip_bfloat16* pkr = kr + ((base + kt + lr) << 7);  // roped K, stride 128, cols 0..63
            kf[0] = *(const bf16x8*)(pk + lg * 8);
            kf[1] = *(const bf16x8*)(pk + 32 + lg * 8);
            kf[2] = *(const bf16x8*)(pkr + lg * 8);
            kf[3] = *(const bf16x8*)(pkr + 32 + lg * 8);
        }
        f16x4 vfr[4];  // V^T frags: A row = v (lane&15), k = key (lane>>4)*4+j
#pragma unroll
        for (int vt = 0; vt < 4; ++vt) {
#pragma unroll
            for (int j = 0; j < 4; ++j)
                vfr[vt][j] = vtc[((base + kt + lg * 4 + j) << 10) + h * 64 + vt * 16 + lr];
        }
#pragma unroll
        for (int g = 0; g < 2; ++g) {
            f32x4 sacc = {};
#pragma unroll
            for (int c = 0; c < 4; ++c)
                sacc = __builtin_amdgcn_mfma_f32_16x16x32_bf16(kf[c], qf[g][c], sacc, 0, 0, 0);
            float s0 = sacc[0] * 0.0625f;  // scale = 1/(sqrt(64)+sqrt(64)) = 1/16
            float s1 = sacc[1] * 0.0625f;
            float s2 = sacc[2] * 0.0625f;
            float s3 = sacc[3] * 0.0625f;
            float tmax = fmaxf(fmaxf(s0, s1), fmaxf(s2, s3));
            tmax = fmaxf(tmax, __shfl_xor(tmax, 16));
            tmax = fmaxf(tmax, __shfl_xor(tmax, 32));
            if (tmax > mrun[g] + 8.0f) {  // defer-max (T13)
                float rf = __expf(mrun[g] - tmax);
                mrun[g]  = tmax;
                lrun[g] *= rf;
#pragma unroll
                for (int vt = 0; vt < 4; ++vt) {
                    oacc[g][vt][0] *= rf; oacc[g][vt][1] *= rf;
                    oacc[g][vt][2] *= rf; oacc[g][vt][3] *= rf;
                }
            }
            float p0 = __expf(s0 - mrun[g]);
            float p1 = __expf(s1 - mrun[g]);
            float p2 = __expf(s2 - mrun[g]);
            float p3 = __expf(s3 - mrun[g]);
            float ts = (p0 + p1) + (p2 + p3);
            ts += __shfl_xor(ts, 16);
            ts += __shfl_xor(ts, 32);
            lrun[g] += ts;
            f16x4 pf;
            pf[0] = (_Float16)p0; pf[1] = (_Float16)p1;
            pf[2] = (_Float16)p2; pf[3] = (_Float16)p3;
#pragma unroll
            for (int vt = 0; vt < 4; ++vt)
                oacc[g][vt] = __builtin_amdgcn_mfma_f32_16x16x16f16(vfr[vt], pf, oacc[g][vt], 0, 0, 0);
        }
    }
#pragma unroll
    for (int g = 0; g < 2; ++g) {
        float inv = 1.0f / lrun[g];
        size_t rowoff = (base + qb + g * 16 + lr) << 10;
#pragma unroll
        for (int vt = 0; vt < 4; ++vt)
#pragma unroll
            for (int r = 0; r < 4; ++r)
                outp[rowoff + h * 64 + vt * 16 + lg * 4 + r] =
                    __float2bfloat16(oacc[g][vt][r] * inv);
    }
}

// ---------- launch ----------
extern "C" void kernel_launch(void* const* d_in, const int* in_sizes, int n_in,
                              void* d_out, int out_size, void* d_ws, size_t ws_size,
                              hipStream_t stream) {
    const float* query = (const float*)d_in[0];
    const float* key   = (const float*)d_in[1];
    // d_in[2] (value) is unused by the reference.
    const float* w_dkv = (const float*)d_in[3];
    const float* b_dkv = (const float*)d_in[4];
    const float* w_uk  = (const float*)d_in[5];
    const float* b_uk  = (const float*)d_in[6];
    const float* w_uv  = (const float*)d_in[7];
    const float* b_uv  = (const float*)d_in[8];
    const float* w_dq  = (const float*)d_in[9];
    const float* b_dq  = (const float*)d_in[10];
    const float* w_uq  = (const float*)d_in[11];
    const float* b_uq  = (const float*)d_in[12];
    const float* w_qr  = (const float*)d_in[13];
    const float* b_qr  = (const float*)d_in[14];
    const float* w_kr  = (const float*)d_in[15];
    const float* b_kr  = (const float*)d_in[16];
    const float* w_fc  = (const float*)d_in[17];
    const float* b_fc  = (const float*)d_in[18];

    const int B = 2;
    const int R = in_sizes[0] / 1024;  // B*S = 4096
    const int S = R / B;               // 2048

    char* ws = (char*)d_ws;
    size_t off = 0;
    auto alloc = [&](size_t bytes) -> char* {
        char* p = ws + off;
        off += (bytes + 255) & ~(size_t)255;
        return p;
    };

    __hip_bfloat16* q_bf   = (__hip_bfloat16*)alloc((size_t)R * 1024 * 2);
    __hip_bfloat16* k_bf   = (__hip_bfloat16*)alloc((size_t)R * 1024 * 2);
    __hip_bfloat16* wdkv_t = (__hip_bfloat16*)alloc(512 * 1024 * 2);
    __hip_bfloat16* wuk_t  = (__hip_bfloat16*)alloc(1024 * 512 * 2);
    __hip_bfloat16* wuv_t  = (__hip_bfloat16*)alloc(1024 * 512 * 2);
    __hip_bfloat16* wdq_t  = (__hip_bfloat16*)alloc(512 * 1024 * 2);
    __hip_bfloat16* wuq_t  = (__hip_bfloat16*)alloc(1024 * 512 * 2);
    __hip_bfloat16* wqr_t  = (__hip_bfloat16*)alloc(1024 * 512 * 2);
    __hip_bfloat16* wkr_t  = (__hip_bfloat16*)alloc(128 * 1024 * 2);
    __hip_bfloat16* wfc_t  = (__hip_bfloat16*)alloc(1024 * 1024 * 2);
    float*          bkrp   = (float*)alloc(128 * 4);
    __hip_bfloat16* c_kv   = (__hip_bfloat16*)alloc((size_t)R * 512 * 2);
    __hip_bfloat16* c_q    = (__hip_bfloat16*)alloc((size_t)R * 512 * 2);
    __hip_bfloat16* ktc    = (__hip_bfloat16*)alloc((size_t)R * 1024 * 2);
    _Float16*       vtc    = (_Float16*)alloc((size_t)R * 1024 * 2);
    __hip_bfloat16* qtc    = (__hip_bfloat16*)alloc((size_t)R * 1024 * 2);
    __hip_bfloat16* qrope  = (__hip_bfloat16*)alloc((size_t)R * 1024 * 2);
    __hip_bfloat16* krope  = (__hip_bfloat16*)alloc((size_t)R * 128 * 2);
    __hip_bfloat16* attn_out = q_bf;  // alias: q_bf dead after GEMMs 2 & 7

    // input converts
    cvt_bf16_kernel<<<dim3(R * 1024 / 8 / 256), 256, 0, stream>>>(query, q_bf, R * 1024 / 8);
    cvt_bf16_kernel<<<dim3(R * 1024 / 8 / 256), 256, 0, stream>>>(key, k_bf, R * 1024 / 8);
    // weight transposes (to [N][K] bf16)
    transpose_cvt<<<dim3(16, 8),  256, 0, stream>>>(w_dkv, wdkv_t, 1024, 512, 512);
    transpose_cvt<<<dim3(8, 16),  256, 0, stream>>>(w_uk,  wuk_t,  512, 1024, 1024);
    transpose_cvt<<<dim3(8, 16),  256, 0, stream>>>(w_uv,  wuv_t,  512, 1024, 1024);
    transpose_cvt<<<dim3(16, 8),  256, 0, stream>>>(w_dq,  wdq_t,  1024, 512, 512);
    transpose_cvt<<<dim3(8, 16),  256, 0, stream>>>(w_uq,  wuq_t,  512, 1024, 1024);
    transpose_cvt<<<dim3(8, 16),  256, 0, stream>>>(w_qr,  wqr_t,  512, 1024, 1024);
    transpose_cvt<<<dim3(16, 2),  256, 0, stream>>>(w_kr,  wkr_t,  1024, 64, 128);
    transpose_cvt<<<dim3(16, 16), 256, 0, stream>>>(w_fc,  wfc_t,  1024, 1024, 1024);
    pad_bias_kernel<<<1, 128, 0, stream>>>(b_kr, bkrp, 64, 128);

    // projection GEMMs
    gemm_bt<0><<<dim3(4, R / 128), 256, 0, stream>>>(k_bf, wdkv_t, b_dkv, c_kv, R, 512, 1024);
    gemm_bt<0><<<dim3(4, R / 128), 256, 0, stream>>>(q_bf, wdq_t,  b_dq,  c_q,  R, 512, 1024);
    gemm_bt<0><<<dim3(8, R / 128), 256, 0, stream>>>(c_kv, wuk_t,  b_uk,  ktc,  R, 1024, 512);
    gemm_bt<2><<<dim3(8, R / 128), 256, 0, stream>>>(c_kv, wuv_t,  b_uv,  vtc,  R, 1024, 512);
    gemm_bt<0><<<dim3(8, R / 128), 256, 0, stream>>>(c_q,  wuq_t,  b_uq,  qtc,  R, 1024, 512);
    gemm_bt<0><<<dim3(8, R / 128), 256, 0, stream>>>(c_q,  wqr_t,  b_qr,  qrope, R, 1024, 512);
    gemm_bt<0><<<dim3(1, R / 128), 256, 0, stream>>>(k_bf, wkr_t,  bkrp,  krope, R, 128, 1024);

    // RoPE (in-place)
    rope_kernel<<<dim3((R * 16 * 32 + 255) / 256), 256, 0, stream>>>(qrope, R, 16, 1024, S);
    rope_kernel<<<dim3((R * 1 * 32 + 255) / 256), 256, 0, stream>>>(krope, R, 1, 128, S);

    // attention
    attn_kernel<<<dim3(S / 128, 16, B), 256, 0, stream>>>(qtc, qrope, ktc, krope, vtc, attn_out, S);

    // output projection (f32 to d_out)
    gemm_bt<1><<<dim3(8, R / 128), 256, 0, stream>>>(attn_out, wfc_t, b_fc, (float*)d_out, R, 1024, 1024);
}